// Round 1
// baseline (704.998 us; speedup 1.0000x reference)
//
#include <hip/hip_runtime.h>
#include <math.h>
#include <stdint.h>
#include <stddef.h>

#define N_ENT   40943
#define N_RELC  237
#define RANK    500
#define BATCH   1024
#define NBR     5
#define INSZ    600
#define KPAD    1024
#define SCALE   0.04472135954999579f   /* 1/sqrt(500) */
#define MINN    1e-15f

typedef __attribute__((ext_vector_type(8))) short  short8;
typedef __attribute__((ext_vector_type(8))) __bf16 bf16x8;
typedef __attribute__((ext_vector_type(4))) float  f32x4;

// ---- MFMA wrapper: tolerate either builtin signature (short8 or bf16x8) ----
template <typename V>
static __device__ auto mfma_try(V a, V b, f32x4 c, int)
    -> decltype(__builtin_amdgcn_mfma_f32_16x16x32_bf16(a, b, c, 0, 0, 0)) {
  return __builtin_amdgcn_mfma_f32_16x16x32_bf16(a, b, c, 0, 0, 0);
}
template <typename V>
static __device__ f32x4 mfma_try(V a, V b, f32x4 c, long) {
  bf16x8 ab = __builtin_bit_cast(bf16x8, a);
  bf16x8 bb = __builtin_bit_cast(bf16x8, b);
  return __builtin_amdgcn_mfma_f32_16x16x32_bf16(ab, bb, c, 0, 0, 0);
}
static __device__ inline f32x4 mfma_bf16(short8 a, short8 b, f32x4 c) {
  return mfma_try(a, b, c, 0);
}

static __device__ inline float softplusf(float x) { return log1pf(expf(x)); }
static __device__ inline float artanhf_c(float x) {
  x = fminf(fmaxf(x, -1.0f + 1e-5f), 1.0f - 1e-5f);
  return 0.5f * (log1pf(x) - log1pf(-x));
}
static __device__ inline unsigned short f2bf(float f) {
  union { float f; unsigned int u; } c; c.f = f;
  unsigned int u = c.u;
  return (unsigned short)((u + 0x7FFFu + ((u >> 16) & 1u)) >> 16);
}

// ---------------- K1: T[i][k] = position[h][k]*pvw[h][k]*scale ----------------
__global__ void build_t(const int* __restrict__ x, const float* __restrict__ pos,
                        const float* __restrict__ pvw, float* __restrict__ T) {
  int i = blockIdx.x;
  int h = x[3 * i];
  const float* p = pos + (size_t)h * INSZ;
  const float* w = pvw + (size_t)h * INSZ;
  float* t = T + (size_t)i * INSZ;
  for (int k = threadIdx.x; k < INSZ; k += blockDim.x)
    t[k] = p[k] * w[k] * SCALE;
}

// ---------------- fp32 tiled GEMM: Y[M][N] = A[M][K] * W[N][K]^T + bias ------
__global__ __launch_bounds__(256) void gemm_fc(
    const float* __restrict__ A, const float* __restrict__ W,
    const float* __restrict__ bias, float* __restrict__ Y,
    int M, int N, int K) {
  __shared__ float As[16][64];
  __shared__ float Bs[16][64];
  int tid = threadIdx.x;
  int tx = tid & 15, ty = tid >> 4;
  int m0 = blockIdx.y * 64, n0 = blockIdx.x * 64;
  float acc[4][4] = {};
  for (int k0 = 0; k0 < K; k0 += 16) {
    int mm = tid & 63, kq = tid >> 6;  // kq 0..3
    int kk = k0 + kq * 4;
    {
      float v0 = 0, v1 = 0, v2 = 0, v3 = 0;
      int gm = m0 + mm;
      if (gm < M) {
        const float* s = A + (size_t)gm * K + kk;
        if (kk + 3 < K) { float4 v = *(const float4*)s; v0 = v.x; v1 = v.y; v2 = v.z; v3 = v.w; }
        else { if (kk < K) v0 = s[0]; if (kk + 1 < K) v1 = s[1]; if (kk + 2 < K) v2 = s[2]; if (kk + 3 < K) v3 = s[3]; }
      }
      As[kq * 4 + 0][mm] = v0; As[kq * 4 + 1][mm] = v1;
      As[kq * 4 + 2][mm] = v2; As[kq * 4 + 3][mm] = v3;
    }
    {
      float v0 = 0, v1 = 0, v2 = 0, v3 = 0;
      int gn = n0 + mm;
      if (gn < N) {
        const float* s = W + (size_t)gn * K + kk;
        if (kk + 3 < K) { float4 v = *(const float4*)s; v0 = v.x; v1 = v.y; v2 = v.z; v3 = v.w; }
        else { if (kk < K) v0 = s[0]; if (kk + 1 < K) v1 = s[1]; if (kk + 2 < K) v2 = s[2]; if (kk + 3 < K) v3 = s[3]; }
      }
      Bs[kq * 4 + 0][mm] = v0; Bs[kq * 4 + 1][mm] = v1;
      Bs[kq * 4 + 2][mm] = v2; Bs[kq * 4 + 3][mm] = v3;
    }
    __syncthreads();
#pragma unroll
    for (int kk2 = 0; kk2 < 16; kk2++) {
      float a0 = As[kk2][ty * 4 + 0], a1 = As[kk2][ty * 4 + 1];
      float a2 = As[kk2][ty * 4 + 2], a3 = As[kk2][ty * 4 + 3];
      float b0 = Bs[kk2][tx * 4 + 0], b1 = Bs[kk2][tx * 4 + 1];
      float b2 = Bs[kk2][tx * 4 + 2], b3 = Bs[kk2][tx * 4 + 3];
      acc[0][0] += a0 * b0; acc[0][1] += a0 * b1; acc[0][2] += a0 * b2; acc[0][3] += a0 * b3;
      acc[1][0] += a1 * b0; acc[1][1] += a1 * b1; acc[1][2] += a1 * b2; acc[1][3] += a1 * b3;
      acc[2][0] += a2 * b0; acc[2][1] += a2 * b1; acc[2][2] += a2 * b2; acc[2][3] += a2 * b3;
      acc[3][0] += a3 * b0; acc[3][1] += a3 * b1; acc[3][2] += a3 * b2; acc[3][3] += a3 * b3;
    }
    __syncthreads();
  }
#pragma unroll
  for (int i2 = 0; i2 < 4; i2++) {
    int gm = m0 + ty * 4 + i2;
    if (gm >= M) continue;
#pragma unroll
    for (int j = 0; j < 4; j++) {
      int gn = n0 + tx * 4 + j;
      if (gn >= N) continue;
      Y[(size_t)gm * N + gn] = acc[i2][j] + bias[gn];
    }
  }
}

// ---------------- LayerNorm (in-place, one block per row of 500) -------------
__global__ __launch_bounds__(256) void lnorm(float* __restrict__ Y,
                                             const float* __restrict__ g,
                                             const float* __restrict__ b) {
  __shared__ float s1[256], s2[256];
  int i = blockIdx.x, tid = threadIdx.x;
  float* y = Y + (size_t)i * RANK;
  float x0 = 0, x1 = 0;
  if (tid < RANK) x0 = y[tid];
  if (tid + 256 < RANK) x1 = y[tid + 256];
  s1[tid] = x0 + x1;
  s2[tid] = x0 * x0 + x1 * x1;
  __syncthreads();
  for (int s = 128; s > 0; s >>= 1) {
    if (tid < s) { s1[tid] += s1[tid + s]; s2[tid] += s2[tid + s]; }
    __syncthreads();
  }
  float mu = s1[0] / (float)RANK;
  float var = s2[0] / (float)RANK - mu * mu;
  float rstd = 1.0f / sqrtf(var + 1e-5f);
  if (tid < RANK) y[tid] = (x0 - mu) * rstd * g[tid] + b[tid];
  if (tid + 256 < RANK) y[tid + 256] = (x1 - mu) * rstd * g[tid + 256] + b[tid + 256];
}

static __device__ float block_reduce(float v, float* sred) {
  int tid = threadIdx.x;
  __syncthreads();
  sred[tid] = v;
  __syncthreads();
  for (int s = 128; s > 0; s >>= 1) {
    if (tid < s) sred[tid] += sred[tid + s];
    __syncthreads();
  }
  return sred[0];
}

// ---------------- per-row finish: attention + hyperbolic + emit bf16 C row ---
__global__ __launch_bounds__(256) void rowfinish(
    const int* __restrict__ x, const int* __restrict__ neighbors,
    const float* __restrict__ emb_e, const float* __restrict__ emb_r,
    const float* __restrict__ emb1_r, const float* __restrict__ context_vec,
    const float* __restrict__ nvw, const float* __restrict__ c1_p,
    const float* __restrict__ c2_p, const float* __restrict__ ab_p,
    const float* __restrict__ fc_mn_w, const float* __restrict__ fc_mn_b,
    const float* __restrict__ Y3, unsigned short* __restrict__ Cmat) {
  __shared__ float lhs_s[RANK];
  __shared__ float rot_s[RANK];
  __shared__ float sred[256];
  int i = blockIdx.x, tid = threadIdx.x;
  int h = x[3 * i], r = x[3 * i + 1];
  const float* lhs_full = emb_e + (size_t)h * 1000;
  const float* rel_full = emb_r + (size_t)r * 1000;
  const float* rel2 = emb1_r + (size_t)r * 1000;

  int ne_i[NBR], nr_i[NBR];
#pragma unroll
  for (int j = 0; j < NBR; j++) {
    ne_i[j] = neighbors[h * 10 + 2 * j];
    nr_i[j] = neighbors[h * 10 + 2 * j + 1];
  }
  // neighbor attention logits: sum_k nvw[nr][k]*emb_r[nr][k]*scale
  float pd[NBR];
#pragma unroll
  for (int j = 0; j < NBR; j++) pd[j] = 0.0f;
  for (int k = tid; k < RANK; k += 256) {
#pragma unroll
    for (int j = 0; j < NBR; j++)
      pd[j] += nvw[(size_t)nr_i[j] * RANK + k] * emb_r[(size_t)nr_i[j] * 1000 + k];
  }
  float dnb[NBR];
#pragma unroll
  for (int j = 0; j < NBR; j++) dnb[j] = block_reduce(pd[j], sred) * SCALE;
  float wn[NBR];
  {
    float mx = dnb[0];
#pragma unroll
    for (int j = 1; j < NBR; j++) mx = fmaxf(mx, dnb[j]);
    float s = 0;
#pragma unroll
    for (int j = 0; j < NBR; j++) { wn[j] = expf(dnb[j] - mx); s += wn[j]; }
#pragma unroll
    for (int j = 0; j < NBR; j++) wn[j] /= s;
  }
  float ab = 0;
#pragma unroll
  for (int j = 0; j < NBR; j++) ab += softplusf(ab_p[nr_i[j]]);
  ab *= 0.2f;
  float mn = softplusf(fc_mn_w[r] + fc_mn_b[0]);

  // lhs = lhs0 + ab*att_n + mn*npos ; norm
  float part = 0;
  for (int k = tid; k < RANK; k += 256) {
    float att = 0;
#pragma unroll
    for (int j = 0; j < NBR; j++) att += wn[j] * emb_e[(size_t)ne_i[j] * 1000 + k];
    float l = lhs_full[k] + ab * att + mn * Y3[(size_t)i * RANK + k];
    lhs_s[k] = l;
    part += l * l;
  }
  float nrm2 = block_reduce(part, sred);
  float norm = fmaxf(sqrtf(nrm2), MINN);
  float c1 = softplusf(c1_p[r]), sc1 = sqrtf(c1);
  float fac = tanhf(sc1 * norm) / (sc1 * norm);
  float gnorm = fac * norm;
  float maxn1 = 0.996f / sc1;
  float a1 = (gnorm > maxn1) ? fac * maxn1 / gnorm : fac;  // head1 = a1*lhs
  float nh1 = fminf(gnorm, maxn1);                          // ||head1||

  // rot1 = givens(rel2, head1); ynorm
  part = 0;
  for (int p = tid; p < RANK / 2; p += 256) {
    float g0 = rel2[2 * p], g1 = rel2[2 * p + 1];
    float gn = fmaxf(sqrtf(g0 * g0 + g1 * g1), MINN);
    g0 /= gn; g1 /= gn;
    float x0 = a1 * lhs_s[2 * p], x1 = a1 * lhs_s[2 * p + 1];
    float r0 = g0 * x0 - g1 * x1;
    float r1 = g0 * x1 + g1 * x0;
    rot_s[2 * p] = r0; rot_s[2 * p + 1] = r1;
    part += r0 * r0 + r1 * r1;
  }
  float yn2 = block_reduce(part, sred);
  float ynorm = fmaxf(sqrtf(yn2), MINN);
  float b1 = artanhf_c(sc1 * ynorm) / (sc1 * ynorm);  // res_c1 = b1*rot1
  float c2 = softplusf(c2_p[r]), sc2 = sqrtf(c2);
  float fac2 = tanhf(sc2 * nh1) / (sc2 * nh1);
  float g2n = fac2 * nh1, maxn2 = 0.996f / sc2;
  float a2 = (g2n > maxn2) ? fac2 * maxn2 / g2n : fac2;           // head2 = a2*head1
  float b2 = artanhf_c(sc2 * a2 * ynorm) / (sc2 * ynorm);          // res_c2 = b2*rot1

  // d0 = scale * <context_vec[r], rot1>; softmax over {b1*d0, b2*d0, d0}
  part = 0;
  for (int k = tid; k < RANK; k += 256) part += context_vec[(size_t)r * RANK + k] * rot_s[k];
  float d0 = block_reduce(part, sred) * SCALE;
  float v1 = b1 * d0, v2 = b2 * d0, v3 = d0;
  float mx = fmaxf(v1, fmaxf(v2, v3));
  float e1 = expf(v1 - mx), e2 = expf(v2 - mx), e3 = expf(v3 - mx);
  float gam = (e1 * b1 + e2 * b2 + e3) / (e1 + e2 + e3);  // att_q = gam*rot1

  unsigned short* crow = Cmat + (size_t)i * KPAD;
  for (int k = tid; k < RANK; k += 256) {
    float aq = gam * rot_s[k];
    float r0 = rel_full[k], rb = rel_full[RANK + k], l1 = lhs_full[RANK + k];
    crow[k] = f2bf(aq * r0 - l1 * rb);
    crow[RANK + k] = f2bf(aq * rb + l1 * r0);
  }
  for (int k = 1000 + tid; k < KPAD; k += 256) crow[k] = 0;
}

// ---------------- optional pre-convert emb_e -> bf16 padded [N_ENT][KPAD] ----
__global__ __launch_bounds__(256) void convert_b(const float* __restrict__ emb_e,
                                                 unsigned short* __restrict__ Bbf) {
  size_t c = (size_t)blockIdx.x * 256 + threadIdx.x;  // 8-element chunk id
  size_t total = (size_t)N_ENT * (KPAD / 8);
  if (c >= total) return;
  int row = (int)(c >> 7);
  int k = (int)(c & 127) * 8;
  unsigned short o[8];
  if (k + 7 < 1000) {
    const float* s = emb_e + (size_t)row * 1000 + k;
#pragma unroll
    for (int j = 0; j < 8; j++) o[j] = f2bf(s[j]);
  } else {
#pragma unroll
    for (int j = 0; j < 8; j++) {
      int kk = k + j;
      o[j] = (kk < 1000) ? f2bf(emb_e[(size_t)row * 1000 + kk]) : (unsigned short)0;
    }
  }
  uint4 v;
  v.x = (unsigned)o[0] | ((unsigned)o[1] << 16);
  v.y = (unsigned)o[2] | ((unsigned)o[3] << 16);
  v.z = (unsigned)o[4] | ((unsigned)o[5] << 16);
  v.w = (unsigned)o[6] | ((unsigned)o[7] << 16);
  *(uint4*)(Bbf + (size_t)row * KPAD + k) = v;
}

// ---------------- main bf16 MFMA GEMM: out[1024][40943] = Cmat * emb_e^T -----
template <bool PRECONV>
__global__ __launch_bounds__(256) void gemm_main(
    const unsigned short* __restrict__ Amat, const float* __restrict__ emb_e,
    const unsigned short* __restrict__ Bbf, float* __restrict__ out) {
  __shared__ unsigned short As[128 * 32];
  __shared__ unsigned short Bs[128 * 32];
  int tid = threadIdx.x;
  int m0 = blockIdx.y * 128;
  int n0 = blockIdx.x * 128;
  int lane = tid & 63, wave = tid >> 6;
  int wm = (wave >> 1) * 64, wn = (wave & 1) * 64;
  int quad = lane >> 4, lrow = lane & 15;
  f32x4 acc[4][4];
#pragma unroll
  for (int mi = 0; mi < 4; mi++)
#pragma unroll
    for (int ni = 0; ni < 4; ni++) {
      acc[mi][ni][0] = 0.0f; acc[mi][ni][1] = 0.0f;
      acc[mi][ni][2] = 0.0f; acc[mi][ni][3] = 0.0f;
    }

  for (int k0 = 0; k0 < KPAD; k0 += 32) {
    // stage A (bf16, already padded): 128x32 = 512 chunks of 8 elems
#pragma unroll
    for (int it = 0; it < 2; it++) {
      int c = tid + it * 256;
      int row = c >> 2, kq = c & 3;
      const uint4* src = (const uint4*)(Amat + (size_t)(m0 + row) * KPAD + k0 + kq * 8);
      *(uint4*)(&As[row * 32 + kq * 8]) = *src;
    }
    if (PRECONV) {
#pragma unroll
      for (int it = 0; it < 2; it++) {
        int c = tid + it * 256;
        int row = c >> 2, kq = c & 3;
        int n = n0 + row;
        if (n > N_ENT - 1) n = N_ENT - 1;  // clamp; junk cols masked at store
        const uint4* src = (const uint4*)(Bbf + (size_t)n * KPAD + k0 + kq * 8);
        *(uint4*)(&Bs[row * 32 + kq * 8]) = *src;
      }
    } else {
#pragma unroll
      for (int it = 0; it < 4; it++) {
        int c = tid + it * 256;
        int row = c >> 3, kq = c & 7;
        int n = n0 + row;
        int kk = k0 + kq * 4;
        float v0 = 0, v1 = 0, v2 = 0, v3 = 0;
        if (n < N_ENT && kk < 1000) {
          float4 v = *(const float4*)(emb_e + (size_t)n * 1000 + kk);
          v0 = v.x; v1 = v.y; v2 = v.z; v3 = v.w;
        }
        uint2 w;
        w.x = (unsigned)f2bf(v0) | ((unsigned)f2bf(v1) << 16);
        w.y = (unsigned)f2bf(v2) | ((unsigned)f2bf(v3) << 16);
        *(uint2*)(&Bs[row * 32 + kq * 4]) = w;
      }
    }
    __syncthreads();
    short8 af[4], bfr[4];
#pragma unroll
    for (int mi = 0; mi < 4; mi++)
      af[mi] = *(const short8*)(&As[(wm + mi * 16 + lrow) * 32 + quad * 8]);
#pragma unroll
    for (int ni = 0; ni < 4; ni++)
      bfr[ni] = *(const short8*)(&Bs[(wn + ni * 16 + lrow) * 32 + quad * 8]);
#pragma unroll
    for (int mi = 0; mi < 4; mi++)
#pragma unroll
      for (int ni = 0; ni < 4; ni++)
        acc[mi][ni] = mfma_bf16(af[mi], bfr[ni], acc[mi][ni]);
    __syncthreads();
  }

#pragma unroll
  for (int mi = 0; mi < 4; mi++) {
#pragma unroll
    for (int ni = 0; ni < 4; ni++) {
      int col = n0 + wn + ni * 16 + lrow;
      if (col >= N_ENT) continue;
      int rowb = m0 + wm + mi * 16 + quad * 4;
#pragma unroll
      for (int i = 0; i < 4; i++)
        out[(size_t)(rowb + i) * N_ENT + col] = acc[mi][ni][i];
    }
  }
}

extern "C" void kernel_launch(void* const* d_in, const int* in_sizes, int n_in,
                              void* d_out, int out_size, void* d_ws, size_t ws_size,
                              hipStream_t stream) {
  const int* x = (const int*)d_in[0];
  const int* neighbors = (const int*)d_in[1];
  const float* position = (const float*)d_in[2];
  const float* emb_e = (const float*)d_in[3];
  const float* emb_r = (const float*)d_in[4];
  const float* emb1_r = (const float*)d_in[5];
  const float* context_vec = (const float*)d_in[6];
  const float* nvw = (const float*)d_in[7];
  const float* pvw = (const float*)d_in[8];
  const float* c1_p = (const float*)d_in[9];
  const float* c2_p = (const float*)d_in[10];
  const float* ab_p = (const float*)d_in[11];
  const float* fc1_w = (const float*)d_in[12];
  const float* fc1_b = (const float*)d_in[13];
  const float* fc2_w = (const float*)d_in[14];
  const float* fc2_b = (const float*)d_in[15];
  const float* fc3_w = (const float*)d_in[16];
  const float* fc3_b = (const float*)d_in[17];
  const float* ln_g = (const float*)d_in[18];
  const float* ln_b = (const float*)d_in[19];
  const float* fc_mn_w = (const float*)d_in[20];
  const float* fc_mn_b = (const float*)d_in[21];
  float* out = (float*)d_out;

  char* ws = (char*)d_ws;
  size_t off = 0;
  auto alloc = [&](size_t bytes) -> void* {
    void* p = (void*)(ws + off);
    off += (bytes + 255) & ~(size_t)255;
    return p;
  };
  float* T = (float*)alloc((size_t)BATCH * INSZ * 4);
  float* Y1 = (float*)alloc((size_t)BATCH * RANK * 4);
  float* Y2 = (float*)alloc((size_t)BATCH * RANK * 4);
  float* Y3 = (float*)alloc((size_t)BATCH * RANK * 4);
  unsigned short* Cmat = (unsigned short*)alloc((size_t)BATCH * KPAD * 2);
  size_t base_need = off;
  size_t bbf_bytes = (size_t)N_ENT * KPAD * 2;
  bool preconv = (ws_size >= base_need + bbf_bytes + 256);
  unsigned short* Bbf = preconv ? (unsigned short*)alloc(bbf_bytes) : nullptr;

  build_t<<<BATCH, 128, 0, stream>>>(x, position, pvw, T);
  gemm_fc<<<dim3(8, 16), 256, 0, stream>>>(T, fc1_w, fc1_b, Y1, BATCH, RANK, INSZ);
  gemm_fc<<<dim3(8, 16), 256, 0, stream>>>(Y1, fc2_w, fc2_b, Y2, BATCH, RANK, RANK);
  lnorm<<<BATCH, 256, 0, stream>>>(Y2, ln_g, ln_b);
  gemm_fc<<<dim3(8, 16), 256, 0, stream>>>(Y2, fc3_w, fc3_b, Y3, BATCH, RANK, RANK);
  rowfinish<<<BATCH, 256, 0, stream>>>(x, neighbors, emb_e, emb_r, emb1_r, context_vec,
                                       nvw, c1_p, c2_p, ab_p, fc_mn_w, fc_mn_b, Y3, Cmat);
  if (preconv) {
    size_t total = (size_t)N_ENT * (KPAD / 8);
    int blocks = (int)((total + 255) / 256);
    convert_b<<<blocks, 256, 0, stream>>>(emb_e, Bbf);
    gemm_main<true><<<dim3(320, 8), 256, 0, stream>>>(Cmat, emb_e, Bbf, out);
  } else {
    gemm_main<false><<<dim3(320, 8), 256, 0, stream>>>(Cmat, emb_e, nullptr, out);
  }
}